// Round 1
// baseline (18105.461 us; speedup 1.0000x reference)
//
#include <hip/hip_runtime.h>
#include <math.h>

#define HDIM 512
#define TPB  128
#define NT   4            // neurons per thread (4*128 = 512)
#define CSTR 24           // LDS row stride in floats (22 used + 2 pad, 16B aligned)
#define NCH  22           // channels per pass: 1 value + 8 grads + 13 hessian pairs
#define NPR  13
#define NRED 57           // per-layer reduction count: 2 + 8 + 8 + 3*13
#define LN_EPS 1e-5f

// Needed Hessian pairs (a<=b, b>=4): 26 total, split 13/13 across passes.
template<int P> struct PairSet;
template<> struct PairSet<0> {
    static constexpr int A[NPR] = {0,1,2,3,4, 0,1,2,3,4,5, 0,1};
    static constexpr int B[NPR] = {4,4,4,4,4, 5,5,5,5,5,5, 6,6};
};
template<> struct PairSet<1> {
    static constexpr int A[NPR] = {2,3,4,5,6, 0,1,2,3,4,5,6,7};
    static constexpr int B[NPR] = {6,6,6,6,6, 7,7,7,7,7,7,7,7};
};

__device__ __forceinline__ float wave_red64(float v) {
    v += __shfl_down(v, 32);
    v += __shfl_down(v, 16);
    v += __shfl_down(v, 8);
    v += __shfl_down(v, 4);
    v += __shfl_down(v, 2);
    v += __shfl_down(v, 1);
    return v;
}

template<int N>
__device__ __forceinline__ void block_reduce(const float (&p)[N], float* wred,
                                             float* fin, int tid) {
    const int wv = tid >> 6, ln = tid & 63;
    #pragma unroll
    for (int k = 0; k < N; ++k) {
        float r = wave_red64(p[k]);
        if (ln == 0) wred[wv * N + k] = r;
    }
    __syncthreads();
    if (tid < N) fin[tid] = wred[tid] + wred[N + tid];
    __syncthreads();
}

// softplus chain + layernorm chain (value/grad/hessian channels), store to LDS state
template<int P>
__device__ __forceinline__ void activate_ln(int tid, float (&acc)[NT][NCH],
        const float* __restrict__ g, const float* __restrict__ be,
        float* __restrict__ sbuf, float* __restrict__ wred, float* __restrict__ fin)
{
    float p[NRED];
    #pragma unroll
    for (int k = 0; k < NRED; ++k) p[k] = 0.f;

    #pragma unroll
    for (int m = 0; m < NT; ++m) {
        const float pv  = acc[m][0];
        const float e   = expf(-fabsf(pv));
        const float sig = (pv >= 0.f) ? (1.f / (1.f + e)) : (e / (1.f + e));
        const float h   = fmaxf(pv, 0.f) + log1pf(e);
        const float spp = sig * (1.f - sig);
        // hessian chain first (uses pre-softplus grads)
        #pragma unroll
        for (int t = 0; t < NPR; ++t) {
            const int a = PairSet<P>::A[t], b = PairSet<P>::B[t];
            acc[m][9+t] = sig * acc[m][9+t] + spp * acc[m][1+a] * acc[m][1+b];
        }
        #pragma unroll
        for (int a = 0; a < 8; ++a) acc[m][1+a] *= sig;
        acc[m][0] = h;

        // moment partials: S_h, S_h2, Sum g_a, Sum h*g_a, Sum hh_t, Sum g_a g_b, Sum h*hh_t
        p[0] += h;
        p[1] += h * h;
        #pragma unroll
        for (int a = 0; a < 8; ++a) { p[2+a] += acc[m][1+a]; p[10+a] += h * acc[m][1+a]; }
        #pragma unroll
        for (int t = 0; t < NPR; ++t) {
            const int a = PairSet<P>::A[t], b = PairSet<P>::B[t];
            p[18+t] += acc[m][9+t];
            p[31+t] += acc[m][1+a] * acc[m][1+b];
            p[44+t] += h * acc[m][9+t];
        }
    }

    block_reduce<NRED>(p, wred, fin, tid);

    const float invH = 1.f / HDIM;
    const float mean = fin[0] * invH;
    const float var  = fin[1] * invH - mean * mean;
    const float rs   = rsqrtf(var + LN_EPS);          // 1/sigma
    float mdot[8], sdot[8];
    #pragma unroll
    for (int a = 0; a < 8; ++a) {
        mdot[a] = fin[2+a] * invH;                    // mean(g_a)
        sdot[a] = (fin[10+a] * invH - mean * mdot[a]) * rs;  // sigma_dot_a
    }
    float mdd[NPR], cy[NPR];
    #pragma unroll
    for (int t = 0; t < NPR; ++t) {
        const int a = PairSet<P>::A[t], b = PairSet<P>::B[t];
        mdd[t] = fin[18+t] * invH;                    // mean(hh)
        const float mcc = fin[31+t] * invH - mdot[a] * mdot[b];  // mean(cd_a cd_b)
        const float mch = fin[44+t] * invH - mean * mdd[t];      // mean(c * hh)
        const float vdd = 2.f * (mcc + mch);          // var_ddot
        const float sdd = (0.5f * vdd - sdot[a] * sdot[b]) * rs; // sigma_ddot
        cy[t] = 2.f * sdot[a] * sdot[b] * rs * rs - sdd * rs;    // coeff of y
    }

    #pragma unroll
    for (int m = 0; m < NT; ++m) {
        const int i = tid + TPB * m;
        const float gi = g[i], bi = be[i];
        const float h = acc[m][0];
        const float c = h - mean;
        const float y = c * rs;
        float* row = sbuf + i * CSTR;
        row[0] = y * gi + bi;
        float cd[8];
        #pragma unroll
        for (int a = 0; a < 8; ++a) {
            cd[a] = acc[m][1+a] - mdot[a];
            row[1+a] = (cd[a] - y * sdot[a]) * rs * gi;
        }
        #pragma unroll
        for (int t = 0; t < NPR; ++t) {
            const int a = PairSet<P>::A[t], b = PairSet<P>::B[t];
            const float cdd = acc[m][9+t] - mdd[t];
            const float ydd = cdd * rs - (cd[a]*sdot[b] + cd[b]*sdot[a]) * rs * rs
                              + y * cy[t];
            row[9+t] = ydd * gi;
        }
    }
}

// next-layer linear from LDS state: acc[m][ch] = b (value only) + sum_j W[i][j]*state[j][ch]
__device__ __forceinline__ void gemm_layer(int tid, float (&acc)[NT][NCH],
        const float* __restrict__ W, const float* __restrict__ b,
        const float* __restrict__ sbuf)
{
    #pragma unroll
    for (int m = 0; m < NT; ++m) {
        #pragma unroll
        for (int ch = 0; ch < NCH; ++ch) acc[m][ch] = 0.f;
        acc[m][0] = b[tid + TPB * m];
    }
    const float* wr[NT];
    #pragma unroll
    for (int m = 0; m < NT; ++m) wr[m] = W + (size_t)(tid + TPB * m) * HDIM;

    for (int j = 0; j < HDIM; j += 4) {
        float4 w[NT];
        #pragma unroll
        for (int m = 0; m < NT; ++m) w[m] = *(const float4*)(wr[m] + j);
        #pragma unroll
        for (int r = 0; r < 4; ++r) {
            const float4* sr = (const float4*)(sbuf + (j + r) * CSTR);
            const float4 s0 = sr[0], s1 = sr[1], s2 = sr[2];
            const float4 s3 = sr[3], s4 = sr[4], s5 = sr[5];
            const float sv[CSTR] = { s0.x,s0.y,s0.z,s0.w, s1.x,s1.y,s1.z,s1.w,
                                     s2.x,s2.y,s2.z,s2.w, s3.x,s3.y,s3.z,s3.w,
                                     s4.x,s4.y,s4.z,s4.w, s5.x,s5.y,s5.z,s5.w };
            #pragma unroll
            for (int m = 0; m < NT; ++m) {
                const float wm = (r == 0) ? w[m].x : (r == 1) ? w[m].y
                               : (r == 2) ? w[m].z : w[m].w;
                #pragma unroll
                for (int ch = 0; ch < NCH; ++ch)
                    acc[m][ch] = fmaf(wm, sv[ch], acc[m][ch]);
            }
        }
    }
}

template<int P>
__device__ void run_pass(int tid, const float (&q)[8],
        const float* __restrict__ W0, const float* __restrict__ b0,
        const float* __restrict__ g0, const float* __restrict__ be0,
        const float* __restrict__ W1, const float* __restrict__ b1,
        const float* __restrict__ g1, const float* __restrict__ be1,
        const float* __restrict__ W2, const float* __restrict__ b2,
        const float* __restrict__ g2, const float* __restrict__ be2,
        const float* __restrict__ W3,
        float* sbuf, float* wred, float* fin, float* sJ, float* sH)
{
    float acc[NT][NCH];

    // ---- layer 0: q (8) -> 512; grads of linear output are W0 rows, hessian 0
    #pragma unroll
    for (int m = 0; m < NT; ++m) {
        const int i = tid + TPB * m;
        const float4 wa = *(const float4*)(W0 + i * 8);
        const float4 wb = *(const float4*)(W0 + i * 8 + 4);
        float pv = b0[i]
            + wa.x*q[0] + wa.y*q[1] + wa.z*q[2] + wa.w*q[3]
            + wb.x*q[4] + wb.y*q[5] + wb.z*q[6] + wb.w*q[7];
        acc[m][0] = pv;
        acc[m][1] = wa.x; acc[m][2] = wa.y; acc[m][3] = wa.z; acc[m][4] = wa.w;
        acc[m][5] = wb.x; acc[m][6] = wb.y; acc[m][7] = wb.z; acc[m][8] = wb.w;
        #pragma unroll
        for (int t = 0; t < NPR; ++t) acc[m][9+t] = 0.f;
    }
    activate_ln<P>(tid, acc, g0, be0, sbuf, wred, fin);
    __syncthreads();

    // ---- layers 1 and 2
    gemm_layer(tid, acc, W1, b1, sbuf);
    activate_ln<P>(tid, acc, g1, be1, sbuf, wred, fin);
    __syncthreads();

    gemm_layer(tid, acc, W2, b2, sbuf);
    activate_ln<P>(tid, acc, g2, be2, sbuf, wred, fin);
    __syncthreads();

    // ---- final linear (scalar): channels = [f, J_0..7, Hpair_0..12]
    float pf[NCH];
    #pragma unroll
    for (int ch = 0; ch < NCH; ++ch) pf[ch] = 0.f;
    #pragma unroll
    for (int m = 0; m < NT; ++m) {
        const int i = tid + TPB * m;
        const float w3 = W3[i];
        const float* row = sbuf + i * CSTR;
        #pragma unroll
        for (int ch = 0; ch < NCH; ++ch) pf[ch] += w3 * row[ch];
    }
    block_reduce<NCH>(pf, wred, fin, tid);
    if (tid == 0) {
        if (P == 0) {
            #pragma unroll
            for (int a = 0; a < 8; ++a) sJ[a] = fin[1 + a];
        }
        #pragma unroll
        for (int t = 0; t < NPR; ++t) sH[P * NPR + t] = fin[9 + t];
    }
    __syncthreads();
}

__global__ __launch_bounds__(TPB)
void lnn_kernel(const float* __restrict__ x,
    const float* __restrict__ W0, const float* __restrict__ b0,
    const float* __restrict__ g0, const float* __restrict__ be0,
    const float* __restrict__ W1, const float* __restrict__ b1,
    const float* __restrict__ g1, const float* __restrict__ be1,
    const float* __restrict__ W2, const float* __restrict__ b2,
    const float* __restrict__ g2, const float* __restrict__ be2,
    const float* __restrict__ W3, float* __restrict__ out)
{
    __shared__ float sbuf[HDIM * CSTR];   // 49152 B state
    __shared__ float wred[2 * NRED];
    __shared__ float fin[NRED];
    __shared__ float sJ[8];
    __shared__ float sH[26];              // global pair order: b=4(5), b=5(6), b=6(7), b=7(8)

    const int tid = threadIdx.x;
    const long sample = blockIdx.x;

    float q[8];
    #pragma unroll
    for (int a = 0; a < 8; ++a) q[a] = x[sample * 8 + a];

    run_pass<0>(tid, q, W0,b0,g0,be0, W1,b1,g1,be1, W2,b2,g2,be2, W3,
                sbuf, wred, fin, sJ, sH);
    run_pass<1>(tid, q, W0,b0,g0,be0, W1,b1,g1,be1, W2,b2,g2,be2, W3,
                sbuf, wred, fin, sJ, sH);

    if (tid == 0) {
        // pair index: idx(a,b) = off[b-4] + a  (a absolute, a<=b, b>=4)
        const int off[4] = {0, 5, 11, 18};
        double Hd[26];
        for (int t = 0; t < 26; ++t) Hd[t] = (double)sH[t];
        // rhs_k = J_k - sum_{j<4} H[j][4+k] * qd_j
        double r[4];
        for (int k = 0; k < 4; ++k) {
            double s = (double)sJ[k];
            for (int j = 0; j < 4; ++j) s -= Hd[off[k] + j] * (double)q[4 + j];
            r[k] = s;
        }
        // M[j][k] = H[4+j][4+k]
        double A[4][5];
        for (int jj = 0; jj < 4; ++jj) {
            for (int k = 0; k < 4; ++k) {
                const int lo = (jj < k ? jj : k) + 4;
                const int hi = (jj < k ? k : jj) + 4;
                A[jj][k] = Hd[off[hi - 4] + lo];
            }
            A[jj][4] = r[jj];
        }
        // Gauss-Jordan with partial pivoting (f64)
        for (int c = 0; c < 4; ++c) {
            int pr = c; double mx = fabs(A[c][c]);
            for (int rr = c + 1; rr < 4; ++rr)
                if (fabs(A[rr][c]) > mx) { mx = fabs(A[rr][c]); pr = rr; }
            if (pr != c)
                for (int cc = c; cc < 5; ++cc) {
                    double t = A[c][cc]; A[c][cc] = A[pr][cc]; A[pr][cc] = t;
                }
            const double pinv = 1.0 / A[c][c];
            for (int rr = 0; rr < 4; ++rr) if (rr != c) {
                const double f = A[rr][c] * pinv;
                for (int cc = c; cc < 5; ++cc) A[rr][cc] -= f * A[c][cc];
            }
        }
        #pragma unroll
        for (int k = 0; k < 4; ++k)
            out[sample * 4 + k] = (float)(A[k][4] / A[k][k]);
    }
}

extern "C" void kernel_launch(void* const* d_in, const int* in_sizes, int n_in,
                              void* d_out, int out_size, void* d_ws, size_t ws_size,
                              hipStream_t stream) {
    const float* x   = (const float*)d_in[0];
    const float* W0  = (const float*)d_in[1];
    const float* b0  = (const float*)d_in[2];
    const float* g0  = (const float*)d_in[3];
    const float* be0 = (const float*)d_in[4];
    const float* W1  = (const float*)d_in[5];
    const float* b1  = (const float*)d_in[6];
    const float* g1  = (const float*)d_in[7];
    const float* be1 = (const float*)d_in[8];
    const float* W2  = (const float*)d_in[9];
    const float* b2  = (const float*)d_in[10];
    const float* g2  = (const float*)d_in[11];
    const float* be2 = (const float*)d_in[12];
    const float* W3  = (const float*)d_in[13];
    float* out = (float*)d_out;

    const int B = in_sizes[0] / 8;   // 16384
    hipLaunchKernelGGL(lnn_kernel, dim3(B), dim3(TPB), 0, stream,
                       x, W0, b0, g0, be0, W1, b1, g1, be1,
                       W2, b2, g2, be2, W3, out);
}

// Round 2
// 17748.132 us; speedup vs baseline: 1.0201x; 1.0201x over previous
//
#include <hip/hip_runtime.h>
#include <math.h>

#define HDIM 512
#define TPB  256
#define NT   2            // neurons per thread (2*256 = 512)
#define NWV  (TPB/64)     // waves per block = 4
#define CSTR 24           // LDS row stride in floats (22 used + 2 pad, 16B aligned)
#define NCH  22           // channels per pass: 1 value + 8 grads + 13 hessian pairs
#define NPR  13
#define NRED 57           // per-layer reduction count: 2 + 8 + 8 + 3*13
#define LN_EPS 1e-5f

// Needed Hessian pairs (a<=b, b>=4): 26 total, split 13/13 across passes.
template<int P> struct PairSet;
template<> struct PairSet<0> {
    static constexpr int A[NPR] = {0,1,2,3,4, 0,1,2,3,4,5, 0,1};
    static constexpr int B[NPR] = {4,4,4,4,4, 5,5,5,5,5,5, 6,6};
};
template<> struct PairSet<1> {
    static constexpr int A[NPR] = {2,3,4,5,6, 0,1,2,3,4,5,6,7};
    static constexpr int B[NPR] = {6,6,6,6,6, 7,7,7,7,7,7,7,7};
};

__device__ __forceinline__ float wave_red64(float v) {
    v += __shfl_down(v, 32);
    v += __shfl_down(v, 16);
    v += __shfl_down(v, 8);
    v += __shfl_down(v, 4);
    v += __shfl_down(v, 2);
    v += __shfl_down(v, 1);
    return v;
}

template<int N>
__device__ __forceinline__ void block_reduce(const float (&p)[N], float* wred,
                                             float* fin, int tid) {
    const int wv = tid >> 6, ln = tid & 63;
    #pragma unroll
    for (int k = 0; k < N; ++k) {
        float r = wave_red64(p[k]);
        if (ln == 0) wred[wv * N + k] = r;
    }
    __syncthreads();
    if (tid < N)
        fin[tid] = (wred[tid] + wred[N + tid]) + (wred[2*N + tid] + wred[3*N + tid]);
    __syncthreads();
}

// softplus chain + layernorm chain (value/grad/hessian channels), store to LDS state
template<int P>
__device__ __forceinline__ void activate_ln(int tid, float (&acc)[NT][NCH],
        const float* __restrict__ g, const float* __restrict__ be,
        float* __restrict__ sbuf, float* __restrict__ wred, float* __restrict__ fin)
{
    float p[NRED];
    #pragma unroll
    for (int k = 0; k < NRED; ++k) p[k] = 0.f;

    #pragma unroll
    for (int m = 0; m < NT; ++m) {
        const float pv  = acc[m][0];
        const float e   = expf(-fabsf(pv));
        const float sig = (pv >= 0.f) ? (1.f / (1.f + e)) : (e / (1.f + e));
        const float h   = fmaxf(pv, 0.f) + log1pf(e);
        const float spp = sig * (1.f - sig);
        // hessian chain first (uses pre-softplus grads)
        #pragma unroll
        for (int t = 0; t < NPR; ++t) {
            const int a = PairSet<P>::A[t], b = PairSet<P>::B[t];
            acc[m][9+t] = sig * acc[m][9+t] + spp * acc[m][1+a] * acc[m][1+b];
        }
        #pragma unroll
        for (int a = 0; a < 8; ++a) acc[m][1+a] *= sig;
        acc[m][0] = h;

        // moment partials: S_h, S_h2, Sum g_a, Sum h*g_a, Sum hh_t, Sum g_a g_b, Sum h*hh_t
        p[0] += h;
        p[1] += h * h;
        #pragma unroll
        for (int a = 0; a < 8; ++a) { p[2+a] += acc[m][1+a]; p[10+a] += h * acc[m][1+a]; }
        #pragma unroll
        for (int t = 0; t < NPR; ++t) {
            const int a = PairSet<P>::A[t], b = PairSet<P>::B[t];
            p[18+t] += acc[m][9+t];
            p[31+t] += acc[m][1+a] * acc[m][1+b];
            p[44+t] += h * acc[m][9+t];
        }
    }

    block_reduce<NRED>(p, wred, fin, tid);

    const float invH = 1.f / HDIM;
    const float mean = fin[0] * invH;
    const float var  = fin[1] * invH - mean * mean;
    const float rs   = rsqrtf(var + LN_EPS);          // 1/sigma
    float mdot[8], sdot[8];
    #pragma unroll
    for (int a = 0; a < 8; ++a) {
        mdot[a] = fin[2+a] * invH;                    // mean(g_a)
        sdot[a] = (fin[10+a] * invH - mean * mdot[a]) * rs;  // sigma_dot_a
    }
    float mdd[NPR], cy[NPR];
    #pragma unroll
    for (int t = 0; t < NPR; ++t) {
        const int a = PairSet<P>::A[t], b = PairSet<P>::B[t];
        mdd[t] = fin[18+t] * invH;                    // mean(hh)
        const float mcc = fin[31+t] * invH - mdot[a] * mdot[b];  // mean(cd_a cd_b)
        const float mch = fin[44+t] * invH - mean * mdd[t];      // mean(c * hh)
        const float vdd = 2.f * (mcc + mch);          // var_ddot
        const float sdd = (0.5f * vdd - sdot[a] * sdot[b]) * rs; // sigma_ddot
        cy[t] = 2.f * sdot[a] * sdot[b] * rs * rs - sdd * rs;    // coeff of y
    }

    #pragma unroll
    for (int m = 0; m < NT; ++m) {
        const int i = tid + TPB * m;
        const float gi = g[i], bi = be[i];
        const float h = acc[m][0];
        const float c = h - mean;
        const float y = c * rs;
        float* row = sbuf + i * CSTR;
        row[0] = y * gi + bi;
        float cd[8];
        #pragma unroll
        for (int a = 0; a < 8; ++a) {
            cd[a] = acc[m][1+a] - mdot[a];
            row[1+a] = (cd[a] - y * sdot[a]) * rs * gi;
        }
        #pragma unroll
        for (int t = 0; t < NPR; ++t) {
            const int a = PairSet<P>::A[t], b = PairSet<P>::B[t];
            const float cdd = acc[m][9+t] - mdd[t];
            const float ydd = cdd * rs - (cd[a]*sdot[b] + cd[b]*sdot[a]) * rs * rs
                              + y * cy[t];
            row[9+t] = ydd * gi;
        }
    }
}

// next-layer linear from LDS state: acc[m][ch] = b (value only) + sum_j W[i][j]*state[j][ch]
__device__ __forceinline__ void gemm_layer(int tid, float (&acc)[NT][NCH],
        const float* __restrict__ W, const float* __restrict__ b,
        const float* __restrict__ sbuf)
{
    #pragma unroll
    for (int m = 0; m < NT; ++m) {
        #pragma unroll
        for (int ch = 0; ch < NCH; ++ch) acc[m][ch] = 0.f;
        acc[m][0] = b[tid + TPB * m];
    }
    const float* wr[NT];
    #pragma unroll
    for (int m = 0; m < NT; ++m) wr[m] = W + (size_t)(tid + TPB * m) * HDIM;

    for (int j = 0; j < HDIM; j += 4) {
        float4 w[NT];
        #pragma unroll
        for (int m = 0; m < NT; ++m) w[m] = *(const float4*)(wr[m] + j);
        #pragma unroll
        for (int r = 0; r < 4; ++r) {
            const float4* sr = (const float4*)(sbuf + (j + r) * CSTR);
            const float4 s0 = sr[0], s1 = sr[1], s2 = sr[2];
            const float4 s3 = sr[3], s4 = sr[4], s5 = sr[5];
            const float sv[CSTR] = { s0.x,s0.y,s0.z,s0.w, s1.x,s1.y,s1.z,s1.w,
                                     s2.x,s2.y,s2.z,s2.w, s3.x,s3.y,s3.z,s3.w,
                                     s4.x,s4.y,s4.z,s4.w, s5.x,s5.y,s5.z,s5.w };
            #pragma unroll
            for (int m = 0; m < NT; ++m) {
                const float wm = (r == 0) ? w[m].x : (r == 1) ? w[m].y
                               : (r == 2) ? w[m].z : w[m].w;
                #pragma unroll
                for (int ch = 0; ch < NCH; ++ch)
                    acc[m][ch] = fmaf(wm, sv[ch], acc[m][ch]);
            }
        }
    }
}

template<int P>
__device__ void run_pass(int tid, const float (&q)[8],
        const float* __restrict__ W0, const float* __restrict__ b0,
        const float* __restrict__ g0, const float* __restrict__ be0,
        const float* __restrict__ W1, const float* __restrict__ b1,
        const float* __restrict__ g1, const float* __restrict__ be1,
        const float* __restrict__ W2, const float* __restrict__ b2,
        const float* __restrict__ g2, const float* __restrict__ be2,
        const float* __restrict__ W3,
        float* sbuf, float* wred, float* fin, float* sJ, float* sH)
{
    float acc[NT][NCH];

    // ---- layer 0: q (8) -> 512; grads of linear output are W0 rows, hessian 0
    #pragma unroll
    for (int m = 0; m < NT; ++m) {
        const int i = tid + TPB * m;
        const float4 wa = *(const float4*)(W0 + i * 8);
        const float4 wb = *(const float4*)(W0 + i * 8 + 4);
        float pv = b0[i]
            + wa.x*q[0] + wa.y*q[1] + wa.z*q[2] + wa.w*q[3]
            + wb.x*q[4] + wb.y*q[5] + wb.z*q[6] + wb.w*q[7];
        acc[m][0] = pv;
        acc[m][1] = wa.x; acc[m][2] = wa.y; acc[m][3] = wa.z; acc[m][4] = wa.w;
        acc[m][5] = wb.x; acc[m][6] = wb.y; acc[m][7] = wb.z; acc[m][8] = wb.w;
        #pragma unroll
        for (int t = 0; t < NPR; ++t) acc[m][9+t] = 0.f;
    }
    activate_ln<P>(tid, acc, g0, be0, sbuf, wred, fin);
    __syncthreads();

    // ---- layers 1 and 2
    gemm_layer(tid, acc, W1, b1, sbuf);
    activate_ln<P>(tid, acc, g1, be1, sbuf, wred, fin);
    __syncthreads();

    gemm_layer(tid, acc, W2, b2, sbuf);
    activate_ln<P>(tid, acc, g2, be2, sbuf, wred, fin);
    __syncthreads();

    // ---- final linear (scalar): channels = [f, J_0..7, Hpair_0..12]
    float pf[NCH];
    #pragma unroll
    for (int ch = 0; ch < NCH; ++ch) pf[ch] = 0.f;
    #pragma unroll
    for (int m = 0; m < NT; ++m) {
        const int i = tid + TPB * m;
        const float w3 = W3[i];
        const float* row = sbuf + i * CSTR;
        #pragma unroll
        for (int ch = 0; ch < NCH; ++ch) pf[ch] += w3 * row[ch];
    }
    block_reduce<NCH>(pf, wred, fin, tid);
    if (tid == 0) {
        if (P == 0) {
            #pragma unroll
            for (int a = 0; a < 8; ++a) sJ[a] = fin[1 + a];
        }
        #pragma unroll
        for (int t = 0; t < NPR; ++t) sH[P * NPR + t] = fin[9 + t];
    }
    __syncthreads();
}

__global__ __launch_bounds__(TPB)
void lnn_kernel(const float* __restrict__ x,
    const float* __restrict__ W0, const float* __restrict__ b0,
    const float* __restrict__ g0, const float* __restrict__ be0,
    const float* __restrict__ W1, const float* __restrict__ b1,
    const float* __restrict__ g1, const float* __restrict__ be1,
    const float* __restrict__ W2, const float* __restrict__ b2,
    const float* __restrict__ g2, const float* __restrict__ be2,
    const float* __restrict__ W3, float* __restrict__ out)
{
    __shared__ float sbuf[HDIM * CSTR];   // 49152 B state
    __shared__ float wred[NWV * NRED];
    __shared__ float fin[NRED];
    __shared__ float sJ[8];
    __shared__ float sH[26];              // global pair order: b=4(5), b=5(6), b=6(7), b=7(8)

    const int tid = threadIdx.x;
    const long sample = blockIdx.x;

    float q[8];
    #pragma unroll
    for (int a = 0; a < 8; ++a) q[a] = x[sample * 8 + a];

    run_pass<0>(tid, q, W0,b0,g0,be0, W1,b1,g1,be1, W2,b2,g2,be2, W3,
                sbuf, wred, fin, sJ, sH);
    run_pass<1>(tid, q, W0,b0,g0,be0, W1,b1,g1,be1, W2,b2,g2,be2, W3,
                sbuf, wred, fin, sJ, sH);

    if (tid == 0) {
        // pair index: idx(a,b) = off[b-4] + a  (a absolute, a<=b, b>=4)
        const int off[4] = {0, 5, 11, 18};
        double Hd[26];
        for (int t = 0; t < 26; ++t) Hd[t] = (double)sH[t];
        // rhs_k = J_k - sum_{j<4} H[j][4+k] * qd_j
        double r[4];
        for (int k = 0; k < 4; ++k) {
            double s = (double)sJ[k];
            for (int j = 0; j < 4; ++j) s -= Hd[off[k] + j] * (double)q[4 + j];
            r[k] = s;
        }
        // M[j][k] = H[4+j][4+k]
        double A[4][5];
        for (int jj = 0; jj < 4; ++jj) {
            for (int k = 0; k < 4; ++k) {
                const int lo = (jj < k ? jj : k) + 4;
                const int hi = (jj < k ? k : jj) + 4;
                A[jj][k] = Hd[off[hi - 4] + lo];
            }
            A[jj][4] = r[jj];
        }
        // Gauss-Jordan with partial pivoting (f64)
        for (int c = 0; c < 4; ++c) {
            int pr = c; double mx = fabs(A[c][c]);
            for (int rr = c + 1; rr < 4; ++rr)
                if (fabs(A[rr][c]) > mx) { mx = fabs(A[rr][c]); pr = rr; }
            if (pr != c)
                for (int cc = c; cc < 5; ++cc) {
                    double t = A[c][cc]; A[c][cc] = A[pr][cc]; A[pr][cc] = t;
                }
            const double pinv = 1.0 / A[c][c];
            for (int rr = 0; rr < 4; ++rr) if (rr != c) {
                const double f = A[rr][c] * pinv;
                for (int cc = c; cc < 5; ++cc) A[rr][cc] -= f * A[c][cc];
            }
        }
        #pragma unroll
        for (int k = 0; k < 4; ++k)
            out[sample * 4 + k] = (float)(A[k][4] / A[k][k]);
    }
}

extern "C" void kernel_launch(void* const* d_in, const int* in_sizes, int n_in,
                              void* d_out, int out_size, void* d_ws, size_t ws_size,
                              hipStream_t stream) {
    const float* x   = (const float*)d_in[0];
    const float* W0  = (const float*)d_in[1];
    const float* b0  = (const float*)d_in[2];
    const float* g0  = (const float*)d_in[3];
    const float* be0 = (const float*)d_in[4];
    const float* W1  = (const float*)d_in[5];
    const float* b1  = (const float*)d_in[6];
    const float* g1  = (const float*)d_in[7];
    const float* be1 = (const float*)d_in[8];
    const float* W2  = (const float*)d_in[9];
    const float* b2  = (const float*)d_in[10];
    const float* g2  = (const float*)d_in[11];
    const float* be2 = (const float*)d_in[12];
    const float* W3  = (const float*)d_in[13];
    float* out = (float*)d_out;

    const int B = in_sizes[0] / 8;   // 16384
    hipLaunchKernelGGL(lnn_kernel, dim3(B), dim3(TPB), 0, stream,
                       x, W0, b0, g0, be0, W1, b1, g1, be1,
                       W2, b2, g2, be2, W3, out);
}

// Round 3
// 6103.658 us; speedup vs baseline: 2.9663x; 2.9078x over previous
//
#include <hip/hip_runtime.h>
#include <math.h>

#define HDIM 512
#define TPB  256
#define SSTR 516              // LDS f32 row stride (512 + 4 pad)
#define NCH  22               // 1 value + 8 grads + 13 hessian pairs
#define NPR  13
#define NRED 57
#define LN_EPS 1e-5f

typedef _Float16 f16x8 __attribute__((ext_vector_type(8)));
typedef float    f32x4 __attribute__((ext_vector_type(4)));

// Needed Hessian pairs (a<=b, b>=4): 26 total, split 13/13 across passes.
template<int P> struct PairSet;
template<> struct PairSet<0> {
    static constexpr int A[NPR] = {0,1,2,3,4, 0,1,2,3,4,5, 0,1};
    static constexpr int B[NPR] = {4,4,4,4,4, 5,5,5,5,5,5, 6,6};
};
template<> struct PairSet<1> {
    static constexpr int A[NPR] = {2,3,4,5,6, 0,1,2,3,4,5,6,7};
    static constexpr int B[NPR] = {6,6,6,6,6, 7,7,7,7,7,7,7,7};
};

// ---------- DPP wave-64 sum (VALU pipe, not DS). Result valid in lane 63. ----------
template<int CTRL>
__device__ __forceinline__ float dpp_add(float x) {
    int v = __builtin_amdgcn_update_dpp(0, __builtin_bit_cast(int, x),
                                        CTRL, 0xf, 0xf, true);
    return x + __builtin_bit_cast(float, v);
}
__device__ __forceinline__ float wave_sum_dpp(float x) {
    x = dpp_add<0x111>(x);   // row_shr:1
    x = dpp_add<0x112>(x);   // row_shr:2
    x = dpp_add<0x114>(x);   // row_shr:4
    x = dpp_add<0x118>(x);   // row_shr:8  -> lane 15/31/47/63 hold row sums
    x = dpp_add<0x142>(x);   // row_bcast:15 -> lane31 = rows0-1, lane63 = rows2-3
    x = dpp_add<0x143>(x);   // row_bcast:31 -> lane63 = full wave sum
    return x;
}

// ---------- prep: W1,W2 f32 -> hi/lo f16 in MFMA-fragment-contiguous layout ----------
// element (i,j) -> off = (((mt*16+ks)*4+q)*16+m)*8+e ; mt=i>>4,m=i&15,ks=j>>5,q=(j>>3)&3,e=j&7
// lo is scaled by 1024 to stay in f16 normal range (W ~0.04 -> lo ~2e-5 would be subnormal).
__global__ void prep_kernel(const float* __restrict__ W1, const float* __restrict__ W2,
                            _Float16* __restrict__ ws) {
    const int gid  = blockIdx.x * 256 + threadIdx.x;   // 0 .. 2*512*512-1
    const int layer = gid >> 18;
    const int r     = gid & 262143;
    const int i = r >> 9, j = r & 511;
    const float v = (layer ? W2 : W1)[r];
    const _Float16 hi = (_Float16)v;
    const _Float16 lo = (_Float16)((v - (float)hi) * 1024.f);
    const int mt = i >> 4, m = i & 15, ks = j >> 5, q = (j >> 3) & 3, e = j & 7;
    const int off = (((mt * 16 + ks) * 4 + q) * 16 + m) * 8 + e;
    _Float16* base = ws + (size_t)layer * 524288;      // [layer][hi|lo][262144]
    base[off] = hi;
    base[262144 + off] = lo;
}

// ---------- MFMA gemm: D[512, 22] = W * S, result staged back into S (ch-major) ----------
// A = W (M=neuron, K=j) from global fragment layout; B = S (K=j, N=ch) from LDS.
// D = Whi*Shi + (1/1024)*(Whi*Slo' + Wlo'*Shi), lo' = 1024*(x - hi). One accumulator,
// two k-sweeps with a rescale in between (avoids 2x acc registers).
__device__ void gemm_mfma(float* __restrict__ S,
                          const _Float16* __restrict__ Whi,
                          const _Float16* __restrict__ Wlo,
                          int w, int lane)
{
    const int q = lane >> 4, m = lane & 15;
    const int ch0 = m;
    const int ch1 = (16 + m < NCH) ? (16 + m) : (NCH - 1);  // clamp garbage lanes
    f32x4 acc[8][2];
    #pragma unroll
    for (int mi = 0; mi < 8; ++mi) {
        acc[mi][0] = (f32x4){0.f, 0.f, 0.f, 0.f};
        acc[mi][1] = (f32x4){0.f, 0.f, 0.f, 0.f};
    }

    // ---- sweep A: cross terms Whi*Slo' + Wlo'*Shi ----
    #pragma unroll 1
    for (int ks = 0; ks < 16; ++ks) {
        f16x8 Bhi[2], Blo[2];
        #pragma unroll
        for (int nt = 0; nt < 2; ++nt) {
            const int ch = nt ? ch1 : ch0;
            const float* sp = S + ch * SSTR + ks * 32 + q * 8;
            const float4 v0 = *(const float4*)sp;
            const float4 v1 = *(const float4*)(sp + 4);
            const float vv[8] = {v0.x, v0.y, v0.z, v0.w, v1.x, v1.y, v1.z, v1.w};
            #pragma unroll
            for (int e = 0; e < 8; ++e) {
                const _Float16 h = (_Float16)vv[e];
                Bhi[nt][e] = h;
                Blo[nt][e] = (_Float16)((vv[e] - (float)h) * 1024.f);
            }
        }
        #pragma unroll
        for (int mi = 0; mi < 8; ++mi) {
            const size_t fo = ((size_t)((w * 8 + mi) * 16 + ks) * 64 + lane) * 8;
            const f16x8 Ahi = *(const f16x8*)(Whi + fo);
            const f16x8 Alo = *(const f16x8*)(Wlo + fo);
            #pragma unroll
            for (int nt = 0; nt < 2; ++nt) {
                acc[mi][nt] = __builtin_amdgcn_mfma_f32_16x16x32_f16(Ahi, Blo[nt], acc[mi][nt], 0, 0, 0);
                acc[mi][nt] = __builtin_amdgcn_mfma_f32_16x16x32_f16(Alo, Bhi[nt], acc[mi][nt], 0, 0, 0);
            }
        }
    }
    #pragma unroll
    for (int mi = 0; mi < 8; ++mi) {
        acc[mi][0] *= (1.f / 1024.f);
        acc[mi][1] *= (1.f / 1024.f);
    }
    // ---- sweep B: main term Whi*Shi ----
    #pragma unroll 1
    for (int ks = 0; ks < 16; ++ks) {
        f16x8 Bhi[2];
        #pragma unroll
        for (int nt = 0; nt < 2; ++nt) {
            const int ch = nt ? ch1 : ch0;
            const float* sp = S + ch * SSTR + ks * 32 + q * 8;
            const float4 v0 = *(const float4*)sp;
            const float4 v1 = *(const float4*)(sp + 4);
            const float vv[8] = {v0.x, v0.y, v0.z, v0.w, v1.x, v1.y, v1.z, v1.w};
            #pragma unroll
            for (int e = 0; e < 8; ++e) Bhi[nt][e] = (_Float16)vv[e];
        }
        #pragma unroll
        for (int mi = 0; mi < 8; ++mi) {
            const size_t fo = ((size_t)((w * 8 + mi) * 16 + ks) * 64 + lane) * 8;
            const f16x8 Ahi = *(const f16x8*)(Whi + fo);
            #pragma unroll
            for (int nt = 0; nt < 2; ++nt)
                acc[mi][nt] = __builtin_amdgcn_mfma_f32_16x16x32_f16(Ahi, Bhi[nt], acc[mi][nt], 0, 0, 0);
        }
    }

    __syncthreads();   // all waves done reading S
    // stage D (pre-activation) ch-major: D row = mt*16 + q*4 + reg, col = ch
    #pragma unroll
    for (int mi = 0; mi < 8; ++mi) {
        #pragma unroll
        for (int nt = 0; nt < 2; ++nt) {
            const int ch = nt * 16 + m;
            if (ch < NCH) {
                const float4 st = {acc[mi][nt][0], acc[mi][nt][1], acc[mi][nt][2], acc[mi][nt][3]};
                *(float4*)(S + ch * SSTR + (w * 8 + mi) * 16 + q * 4) = st;
            }
        }
    }
    __syncthreads();
}

__device__ __forceinline__ void readback(float (&vals)[2][NCH],
                                         const float* __restrict__ b,
                                         const float* __restrict__ S, int tid)
{
    #pragma unroll
    for (int m = 0; m < 2; ++m) {
        const int j = 2 * tid + m;
        #pragma unroll
        for (int ch = 0; ch < NCH; ++ch) vals[m][ch] = S[ch * SSTR + j];
        vals[m][0] += b[j];
    }
}

// ---------- softplus chain + LN; writes S (ch-major) or accumulates final linear ----------
template<int P, bool FINAL>
__device__ void ln_process(float (&vals)[2][NCH],
        const float* __restrict__ g, const float* __restrict__ be,
        float* __restrict__ S, float* __restrict__ red, float* __restrict__ fin,
        float* __restrict__ sJ, float* __restrict__ sH,
        int tid, int lane, int w, float w3x, float w3y)
{
    float p[NRED];
    #pragma unroll
    for (int k = 0; k < NRED; ++k) p[k] = 0.f;

    #pragma unroll
    for (int m = 0; m < 2; ++m) {
        const float pv  = vals[m][0];
        const float e   = expf(-fabsf(pv));
        const float sig = (pv >= 0.f) ? (1.f / (1.f + e)) : (e / (1.f + e));
        const float h   = fmaxf(pv, 0.f) + log1pf(e);
        const float spp = sig * (1.f - sig);
        #pragma unroll
        for (int t = 0; t < NPR; ++t) {
            const int a = PairSet<P>::A[t], b = PairSet<P>::B[t];
            vals[m][9+t] = sig * vals[m][9+t] + spp * vals[m][1+a] * vals[m][1+b];
        }
        #pragma unroll
        for (int a = 0; a < 8; ++a) vals[m][1+a] *= sig;
        vals[m][0] = h;

        p[0] += h;
        p[1] += h * h;
        #pragma unroll
        for (int a = 0; a < 8; ++a) { p[2+a] += vals[m][1+a]; p[10+a] += h * vals[m][1+a]; }
        #pragma unroll
        for (int t = 0; t < NPR; ++t) {
            const int a = PairSet<P>::A[t], b = PairSet<P>::B[t];
            p[18+t] += vals[m][9+t];
            p[31+t] += vals[m][1+a] * vals[m][1+b];
            p[44+t] += h * vals[m][9+t];
        }
    }

    // reduce 57 sums: DPP within wave, LDS across the 4 waves
    #pragma unroll
    for (int k = 0; k < NRED; ++k) p[k] = wave_sum_dpp(p[k]);
    if (lane == 63) {
        #pragma unroll
        for (int k = 0; k < NRED; ++k) red[w * NRED + k] = p[k];
    }
    __syncthreads();
    if (tid < NRED)
        fin[tid] = (red[tid] + red[NRED + tid]) + (red[2*NRED + tid] + red[3*NRED + tid]);
    __syncthreads();

    const float invH = 1.f / HDIM;
    const float mean = fin[0] * invH;
    const float var  = fin[1] * invH - mean * mean;
    const float rs   = rsqrtf(var + LN_EPS);
    float mdot[8], sdot[8];
    #pragma unroll
    for (int a = 0; a < 8; ++a) {
        mdot[a] = fin[2+a] * invH;
        sdot[a] = (fin[10+a] * invH - mean * mdot[a]) * rs;
    }
    float mdd[NPR], cy[NPR];
    #pragma unroll
    for (int t = 0; t < NPR; ++t) {
        const int a = PairSet<P>::A[t], b = PairSet<P>::B[t];
        mdd[t] = fin[18+t] * invH;
        const float mcc = fin[31+t] * invH - mdot[a] * mdot[b];
        const float mch = fin[44+t] * invH - mean * mdd[t];
        const float vdd = 2.f * (mcc + mch);
        const float sdd = (0.5f * vdd - sdot[a] * sdot[b]) * rs;
        cy[t] = 2.f * sdot[a] * sdot[b] * rs * rs - sdd * rs;
    }

    if (!FINAL) {
        #pragma unroll
        for (int m = 0; m < 2; ++m) {
            const int j = 2 * tid + m;
            const float gi = g[j], bi = be[j];
            const float y = (vals[m][0] - mean) * rs;
            S[0 * SSTR + j] = y * gi + bi;
            float cd[8];
            #pragma unroll
            for (int a = 0; a < 8; ++a) {
                cd[a] = vals[m][1+a] - mdot[a];
                S[(1+a) * SSTR + j] = (cd[a] - y * sdot[a]) * rs * gi;
            }
            #pragma unroll
            for (int t = 0; t < NPR; ++t) {
                const int a = PairSet<P>::A[t], b = PairSet<P>::B[t];
                const float cdd = vals[m][9+t] - mdd[t];
                const float ydd = cdd * rs - (cd[a]*sdot[b] + cd[b]*sdot[a]) * rs * rs
                                  + y * cy[t];
                S[(9+t) * SSTR + j] = ydd * gi;
            }
        }
    } else {
        float pf[NCH];
        #pragma unroll
        for (int k = 0; k < NCH; ++k) pf[k] = 0.f;
        #pragma unroll
        for (int m = 0; m < 2; ++m) {
            const int j = 2 * tid + m;
            const float gi = g[j], bi = be[j];
            const float w3 = m ? w3y : w3x;
            const float y = (vals[m][0] - mean) * rs;
            pf[0] += w3 * (y * gi + bi);
            float cd[8];
            #pragma unroll
            for (int a = 0; a < 8; ++a) {
                cd[a] = vals[m][1+a] - mdot[a];
                pf[1+a] += w3 * ((cd[a] - y * sdot[a]) * rs * gi);
            }
            #pragma unroll
            for (int t = 0; t < NPR; ++t) {
                const int a = PairSet<P>::A[t], b = PairSet<P>::B[t];
                const float cdd = vals[m][9+t] - mdd[t];
                const float ydd = cdd * rs - (cd[a]*sdot[b] + cd[b]*sdot[a]) * rs * rs
                                  + y * cy[t];
                pf[9+t] += w3 * (ydd * gi);
            }
        }
        #pragma unroll
        for (int k = 0; k < NCH; ++k) pf[k] = wave_sum_dpp(pf[k]);
        if (lane == 63) {
            #pragma unroll
            for (int k = 0; k < NCH; ++k) red[w * NRED + k] = pf[k];
        }
        __syncthreads();
        if (tid < NCH)
            fin[tid] = (red[tid] + red[NRED + tid]) + (red[2*NRED + tid] + red[3*NRED + tid]);
        __syncthreads();
        if (tid == 0) {
            if (P == 0) {
                #pragma unroll
                for (int a = 0; a < 8; ++a) sJ[a] = fin[1 + a];
            }
            #pragma unroll
            for (int t = 0; t < NPR; ++t) sH[P * NPR + t] = fin[9 + t];
        }
    }
}

template<int P>
__device__ void run_pass(int tid, int lane, int w, const float (&q)[8],
        const float* __restrict__ W0, const float* __restrict__ b0,
        const float* __restrict__ g0, const float* __restrict__ be0,
        const float* __restrict__ b1, const float* __restrict__ g1,
        const float* __restrict__ be1,
        const float* __restrict__ b2, const float* __restrict__ g2,
        const float* __restrict__ be2,
        const _Float16* __restrict__ Wf,
        float w3x, float w3y,
        float* S, float* red, float* fin, float* sJ, float* sH)
{
    float vals[2][NCH];

    // ---- layer 0: q(8) -> 512 (no gemm); grads = W0 row, hess = 0
    #pragma unroll
    for (int m = 0; m < 2; ++m) {
        const int i = 2 * tid + m;
        const float4 wa = *(const float4*)(W0 + i * 8);
        const float4 wb = *(const float4*)(W0 + i * 8 + 4);
        vals[m][0] = b0[i]
            + wa.x*q[0] + wa.y*q[1] + wa.z*q[2] + wa.w*q[3]
            + wb.x*q[4] + wb.y*q[5] + wb.z*q[6] + wb.w*q[7];
        vals[m][1] = wa.x; vals[m][2] = wa.y; vals[m][3] = wa.z; vals[m][4] = wa.w;
        vals[m][5] = wb.x; vals[m][6] = wb.y; vals[m][7] = wb.z; vals[m][8] = wb.w;
        #pragma unroll
        for (int t = 0; t < NPR; ++t) vals[m][9+t] = 0.f;
    }
    ln_process<P, false>(vals, g0, be0, S, red, fin, sJ, sH, tid, lane, w, w3x, w3y);
    __syncthreads();

    // ---- layer 1
    gemm_mfma(S, Wf, Wf + 262144, w, lane);
    readback(vals, b1, S, tid);
    ln_process<P, false>(vals, g1, be1, S, red, fin, sJ, sH, tid, lane, w, w3x, w3y);
    __syncthreads();

    // ---- layer 2
    gemm_mfma(S, Wf + 524288, Wf + 786432, w, lane);
    readback(vals, b2, S, tid);
    ln_process<P, true>(vals, g2, be2, S, red, fin, sJ, sH, tid, lane, w, w3x, w3y);
    __syncthreads();
}

__global__ __launch_bounds__(TPB, 3)
void lnn_kernel(const float* __restrict__ x,
    const float* __restrict__ W0, const float* __restrict__ b0,
    const float* __restrict__ g0, const float* __restrict__ be0,
    const float* __restrict__ b1, const float* __restrict__ g1,
    const float* __restrict__ be1,
    const float* __restrict__ b2, const float* __restrict__ g2,
    const float* __restrict__ be2,
    const float* __restrict__ W3,
    const _Float16* __restrict__ Wf,
    float* __restrict__ out)
{
    __shared__ __align__(16) float S[NCH * SSTR];   // 45.4 KB: state / D-staging
    __shared__ __align__(16) float red[4 * NRED];
    __shared__ __align__(16) float fin[NRED + 3];
    __shared__ float sJ[8];
    __shared__ float sH[26];

    const int tid  = threadIdx.x;
    const int lane = tid & 63;
    const int w    = tid >> 6;
    const long sample = blockIdx.x;

    float q[8];
    #pragma unroll
    for (int a = 0; a < 8; ++a) q[a] = x[sample * 8 + a];
    const float w3x = W3[2 * tid], w3y = W3[2 * tid + 1];

    run_pass<0>(tid, lane, w, q, W0, b0, g0, be0, b1, g1, be1, b2, g2, be2,
                Wf, w3x, w3y, S, red, fin, sJ, sH);
    run_pass<1>(tid, lane, w, q, W0, b0, g0, be0, b1, g1, be1, b2, g2, be2,
                Wf, w3x, w3y, S, red, fin, sJ, sH);

    if (tid == 0) {
        const int off[4] = {0, 5, 11, 18};
        double Hd[26];
        for (int t = 0; t < 26; ++t) Hd[t] = (double)sH[t];
        double r[4];
        for (int k = 0; k < 4; ++k) {
            double s = (double)sJ[k];
            for (int j = 0; j < 4; ++j) s -= Hd[off[k] + j] * (double)q[4 + j];
            r[k] = s;
        }
        double A[4][5];
        for (int jj = 0; jj < 4; ++jj) {
            for (int k = 0; k < 4; ++k) {
                const int lo = (jj < k ? jj : k) + 4;
                const int hi = (jj < k ? k : jj) + 4;
                A[jj][k] = Hd[off[hi - 4] + lo];
            }
            A[jj][4] = r[jj];
        }
        for (int c = 0; c < 4; ++c) {
            int pr = c; double mx = fabs(A[c][c]);
            for (int rr = c + 1; rr < 4; ++rr)
                if (fabs(A[rr][c]) > mx) { mx = fabs(A[rr][c]); pr = rr; }
            if (pr != c)
                for (int cc = c; cc < 5; ++cc) {
                    double t = A[c][cc]; A[c][cc] = A[pr][cc]; A[pr][cc] = t;
                }
            const double pinv = 1.0 / A[c][c];
            for (int rr = 0; rr < 4; ++rr) if (rr != c) {
                const double f = A[rr][c] * pinv;
                for (int cc = c; cc < 5; ++cc) A[rr][cc] -= f * A[c][cc];
            }
        }
        #pragma unroll
        for (int k = 0; k < 4; ++k)
            out[sample * 4 + k] = (float)(A[k][4] / A[k][k]);
    }
}

extern "C" void kernel_launch(void* const* d_in, const int* in_sizes, int n_in,
                              void* d_out, int out_size, void* d_ws, size_t ws_size,
                              hipStream_t stream) {
    const float* x   = (const float*)d_in[0];
    const float* W0  = (const float*)d_in[1];
    const float* b0  = (const float*)d_in[2];
    const float* g0  = (const float*)d_in[3];
    const float* be0 = (const float*)d_in[4];
    const float* W1  = (const float*)d_in[5];
    const float* b1  = (const float*)d_in[6];
    const float* g1  = (const float*)d_in[7];
    const float* be1 = (const float*)d_in[8];
    const float* W2  = (const float*)d_in[9];
    const float* b2  = (const float*)d_in[10];
    const float* g2  = (const float*)d_in[11];
    const float* be2 = (const float*)d_in[12];
    const float* W3  = (const float*)d_in[13];
    float* out = (float*)d_out;

    _Float16* Wf = (_Float16*)d_ws;   // needs 2 MB: [W1hi|W1lo|W2hi|W2lo]
    const int B = in_sizes[0] / 8;    // 16384

    hipLaunchKernelGGL(prep_kernel, dim3(2048), dim3(256), 0, stream, W1, W2, Wf);
    hipLaunchKernelGGL(lnn_kernel, dim3(B), dim3(TPB), 0, stream,
                       x, W0, b0, g0, be0, b1, g1, be1, b2, g2, be2, W3, Wf, out);
}

// Round 7
// 6017.553 us; speedup vs baseline: 3.0088x; 1.0143x over previous
//
#include <hip/hip_runtime.h>
#include <math.h>

#define HDIM 512
#define TPB  256
#define SSTR 516              // LDS f32 row stride (512 + 4 pad)
#define NCH  22               // 1 value + 8 grads + 13 hessian pairs
#define NPR  13
#define NRED 57
#define LN_EPS 1e-5f

typedef _Float16 f16x8 __attribute__((ext_vector_type(8)));
typedef float    f32x4 __attribute__((ext_vector_type(4)));

// Needed Hessian pairs (a<=b, b>=4): 26 total, split 13/13 across passes.
template<int P> struct PairSet;
template<> struct PairSet<0> {
    static constexpr int A[NPR] = {0,1,2,3,4, 0,1,2,3,4,5, 0,1};
    static constexpr int B[NPR] = {4,4,4,4,4, 5,5,5,5,5,5, 6,6};
};
template<> struct PairSet<1> {
    static constexpr int A[NPR] = {2,3,4,5,6, 0,1,2,3,4,5,6,7};
    static constexpr int B[NPR] = {6,6,6,6,6, 7,7,7,7,7,7,7,7};
};

// ---------- DPP wave-64 sum (VALU pipe, not DS). Result valid in lane 63. ----------
template<int CTRL>
__device__ __forceinline__ float dpp_add(float x) {
    int v = __builtin_amdgcn_update_dpp(0, __builtin_bit_cast(int, x),
                                        CTRL, 0xf, 0xf, true);
    return x + __builtin_bit_cast(float, v);
}
__device__ __forceinline__ float wave_sum_dpp(float x) {
    x = dpp_add<0x111>(x);   // row_shr:1
    x = dpp_add<0x112>(x);   // row_shr:2
    x = dpp_add<0x114>(x);   // row_shr:4
    x = dpp_add<0x118>(x);   // row_shr:8
    x = dpp_add<0x142>(x);   // row_bcast:15
    x = dpp_add<0x143>(x);   // row_bcast:31 -> lane63 = full wave sum
    return x;
}

// ---------- prep: W1,W2 f32 -> hi/lo f16 in MFMA-fragment-contiguous layout ----------
// element (i,j) -> off = (((mt*16+ks)*4+q)*16+m)*8+e
// lo scaled by 1024 to stay in f16 normal range.
__global__ void prep_kernel(const float* __restrict__ W1, const float* __restrict__ W2,
                            _Float16* __restrict__ ws) {
    const int gid  = blockIdx.x * 256 + threadIdx.x;
    const int layer = gid >> 18;
    const int r     = gid & 262143;
    const int i = r >> 9, j = r & 511;
    const float v = (layer ? W2 : W1)[r];
    const _Float16 hi = (_Float16)v;
    const _Float16 lo = (_Float16)((v - (float)hi) * 1024.f);
    const int mt = i >> 4, m = i & 15, ks = j >> 5, q = (j >> 3) & 3, e = j & 7;
    const int off = (((mt * 16 + ks) * 4 + q) * 16 + m) * 8 + e;
    _Float16* base = ws + (size_t)layer * 524288;
    base[off] = hi;
    base[262144 + off] = lo;
}

// ---------- MFMA gemm: D[512, 22] = W * S, result staged back into S (ch-major) ----------
// A = W (M=neuron, K=j) from global fragment layout; B = S (K=j, N=ch) from LDS.
// D = Whi*Shi + (1/1024)*(Whi*Slo + Wlo*Shi), lo = 1024*(x - hi). One accumulator,
// two k-sweeps with a rescale in between (avoids 2x acc registers).
__device__ void gemm_mfma(float* __restrict__ S,
                          const _Float16* __restrict__ Whi,
                          const _Float16* __restrict__ Wlo,
                          int w, int lane)
{
    const int q = lane >> 4, m = lane & 15;
    const int ch0 = m;
    const int ch1 = (16 + m < NCH) ? (16 + m) : (NCH - 1);  // clamp garbage lanes
    f32x4 acc[8][2];
    #pragma unroll
    for (int mi = 0; mi < 8; ++mi) {
        acc[mi][0] = (f32x4){0.f, 0.f, 0.f, 0.f};
        acc[mi][1] = (f32x4){0.f, 0.f, 0.f, 0.f};
    }

    // ---- sweep A: cross terms Whi*Slo + Wlo*Shi ----
    #pragma unroll 1
    for (int ks = 0; ks < 16; ++ks) {
        f16x8 Bhi[2], Blo[2];
        #pragma unroll
        for (int nt = 0; nt < 2; ++nt) {
            const int ch = nt ? ch1 : ch0;
            const float* sp = S + ch * SSTR + ks * 32 + q * 8;
            const float4 v0 = *(const float4*)sp;
            const float4 v1 = *(const float4*)(sp + 4);
            const float vv[8] = {v0.x, v0.y, v0.z, v0.w, v1.x, v1.y, v1.z, v1.w};
            #pragma unroll
            for (int e = 0; e < 8; ++e) {
                const _Float16 h = (_Float16)vv[e];
                Bhi[nt][e] = h;
                Blo[nt][e] = (_Float16)((vv[e] - (float)h) * 1024.f);
            }
        }
        #pragma unroll
        for (int mi = 0; mi < 8; ++mi) {
            const size_t fo = ((size_t)((w * 8 + mi) * 16 + ks) * 64 + lane) * 8;
            const f16x8 Ahi = *(const f16x8*)(Whi + fo);
            const f16x8 Alo = *(const f16x8*)(Wlo + fo);
            acc[mi][0] = __builtin_amdgcn_mfma_f32_16x16x32_f16(Ahi, Blo[0], acc[mi][0], 0, 0, 0);
            acc[mi][0] = __builtin_amdgcn_mfma_f32_16x16x32_f16(Alo, Bhi[0], acc[mi][0], 0, 0, 0);
            acc[mi][1] = __builtin_amdgcn_mfma_f32_16x16x32_f16(Ahi, Blo[1], acc[mi][1], 0, 0, 0);
            acc[mi][1] = __builtin_amdgcn_mfma_f32_16x16x32_f16(Alo, Bhi[1], acc[mi][1], 0, 0, 0);
        }
    }
    #pragma unroll
    for (int mi = 0; mi < 8; ++mi) {
        acc[mi][0] *= (1.f / 1024.f);
        acc[mi][1] *= (1.f / 1024.f);
    }
    // ---- sweep B: main term Whi*Shi ----
    #pragma unroll 1
    for (int ks = 0; ks < 16; ++ks) {
        f16x8 Bhi[2];
        #pragma unroll
        for (int nt = 0; nt < 2; ++nt) {
            const int ch = nt ? ch1 : ch0;
            const float* sp = S + ch * SSTR + ks * 32 + q * 8;
            const float4 v0 = *(const float4*)sp;
            const float4 v1 = *(const float4*)(sp + 4);
            const float vv[8] = {v0.x, v0.y, v0.z, v0.w, v1.x, v1.y, v1.z, v1.w};
            #pragma unroll
            for (int e = 0; e < 8; ++e) Bhi[nt][e] = (_Float16)vv[e];
        }
        #pragma unroll
        for (int mi = 0; mi < 8; ++mi) {
            const size_t fo = ((size_t)((w * 8 + mi) * 16 + ks) * 64 + lane) * 8;
            const f16x8 Ahi = *(const f16x8*)(Whi + fo);
            acc[mi][0] = __builtin_amdgcn_mfma_f32_16x16x32_f16(Ahi, Bhi[0], acc[mi][0], 0, 0, 0);
            acc[mi][1] = __builtin_amdgcn_mfma_f32_16x16x32_f16(Ahi, Bhi[1], acc[mi][1], 0, 0, 0);
        }
    }

    __syncthreads();   // all waves done reading S (f16) -> safe to overwrite with D (f32)
    #pragma unroll
    for (int mi = 0; mi < 8; ++mi) {
        #pragma unroll
        for (int nt = 0; nt < 2; ++nt) {
            const int ch = nt * 16 + m;
            if (ch < NCH) {
                const float4 st = {acc[mi][nt][0], acc[mi][nt][1], acc[mi][nt][2], acc[mi][nt][3]};
                *(float4*)(S + ch * SSTR + (w * 8 + mi) * 16 + q * 4) = st;
            }
        }
    }
    __syncthreads();
}

__device__ __forceinline__ void readback(float (&vals)[2][NCH],
                                         const float* __restrict__ b,
                                         const float* __restrict__ S, int tid)
{
    #pragma unroll
    for (int m = 0; m < 2; ++m) {
        const int j = 2 * tid + m;
        #pragma unroll
        for (int ch = 0; ch < NCH; ++ch) vals[m][ch] = S[ch * SSTR + j];
        vals[m][0] += b[j];
    }
}

// ---------- softplus chain + LN; writes S (ch-major) or accumulates final linear ----------
template<int P, bool FINAL>
__device__ void ln_process(float (&vals)[2][NCH],
        const float* __restrict__ g, const float* __restrict__ be,
        float* __restrict__ S, float* __restrict__ red, float* __restrict__ fin,
        float* __restrict__ sJ, float* __restrict__ sH,
        int tid, int lane, int w, float w3x, float w3y)
{
    float p[NRED];
    #pragma unroll
    for (int k = 0; k < NRED; ++k) p[k] = 0.f;

    #pragma unroll
    for (int m = 0; m < 2; ++m) {
        const float pv  = vals[m][0];
        const float e   = expf(-fabsf(pv));
        const float sig = (pv >= 0.f) ? (1.f / (1.f + e)) : (e / (1.f + e));
        const float h   = fmaxf(pv, 0.f) + log1pf(e);
        const float spp = sig * (1.f - sig);
        #pragma unroll
        for (int t = 0; t < NPR; ++t) {
            const int a = PairSet<P>::A[t], b = PairSet<P>::B[t];
            vals[m][9+t] = sig * vals[m][9+t] + spp * vals[m][1+a] * vals[m][1+b];
        }
        #pragma unroll
        for (int a = 0; a < 8; ++a) vals[m][1+a] *= sig;
        vals[m][0] = h;

        p[0] += h;
        p[1] += h * h;
        #pragma unroll
        for (int a = 0; a < 8; ++a) { p[2+a] += vals[m][1+a]; p[10+a] += h * vals[m][1+a]; }
        #pragma unroll
        for (int t = 0; t < NPR; ++t) {
            const int a = PairSet<P>::A[t], b = PairSet<P>::B[t];
            p[18+t] += vals[m][9+t];
            p[31+t] += vals[m][1+a] * vals[m][1+b];
            p[44+t] += h * vals[m][9+t];
        }
    }

    #pragma unroll
    for (int k = 0; k < NRED; ++k) p[k] = wave_sum_dpp(p[k]);
    if (lane == 63) {
        #pragma unroll
        for (int k = 0; k < NRED; ++k) red[w * NRED + k] = p[k];
    }
    __syncthreads();
    if (tid < NRED)
        fin[tid] = (red[tid] + red[NRED + tid]) + (red[2*NRED + tid] + red[3*NRED + tid]);
    __syncthreads();

    const float invH = 1.f / HDIM;
    const float mean = fin[0] * invH;
    const float var  = fin[1] * invH - mean * mean;
    const float rs   = rsqrtf(var + LN_EPS);
    float mdot[8], sdot[8];
    #pragma unroll
    for (int a = 0; a < 8; ++a) {
        mdot[a] = fin[2+a] * invH;
        sdot[a] = (fin[10+a] * invH - mean * mdot[a]) * rs;
    }
    float mdd[NPR], cy[NPR];
    #pragma unroll
    for (int t = 0; t < NPR; ++t) {
        const int a = PairSet<P>::A[t], b = PairSet<P>::B[t];
        mdd[t] = fin[18+t] * invH;
        const float mcc = fin[31+t] * invH - mdot[a] * mdot[b];
        const float mch = fin[44+t] * invH - mean * mdd[t];
        const float vdd = 2.f * (mcc + mch);
        const float sdd = (0.5f * vdd - sdot[a] * sdot[b]) * rs;
        cy[t] = 2.f * sdot[a] * sdot[b] * rs * rs - sdd * rs;
    }

    if (!FINAL) {
        #pragma unroll
        for (int m = 0; m < 2; ++m) {
            const int j = 2 * tid + m;
            const float gi = g[j], bi = be[j];
            const float y = (vals[m][0] - mean) * rs;
            S[0 * SSTR + j] = y * gi + bi;
            float cd[8];
            #pragma unroll
            for (int a = 0; a < 8; ++a) {
                cd[a] = vals[m][1+a] - mdot[a];
                S[(1+a) * SSTR + j] = (cd[a] - y * sdot[a]) * rs * gi;
            }
            #pragma unroll
            for (int t = 0; t < NPR; ++t) {
                const int a = PairSet<P>::A[t], b = PairSet<P>::B[t];
                const float cdd = vals[m][9+t] - mdd[t];
                const float ydd = cdd * rs - (cd[a]*sdot[b] + cd[b]*sdot[a]) * rs * rs
                                  + y * cy[t];
                S[(9+t) * SSTR + j] = ydd * gi;
            }
        }
    } else {
        float pf[NCH];
        #pragma unroll
        for (int k = 0; k < NCH; ++k) pf[k] = 0.f;
        #pragma unroll
        for (int m = 0; m < 2; ++m) {
            const int j = 2 * tid + m;
            const float gi = g[j], bi = be[j];
            const float w3 = m ? w3y : w3x;
            const float y = (vals[m][0] - mean) * rs;
            pf[0] += w3 * (y * gi + bi);
            float cd[8];
            #pragma unroll
            for (int a = 0; a < 8; ++a) {
                cd[a] = vals[m][1+a] - mdot[a];
                pf[1+a] += w3 * ((cd[a] - y * sdot[a]) * rs * gi);
            }
            #pragma unroll
            for (int t = 0; t < NPR; ++t) {
                const int a = PairSet<P>::A[t], b = PairSet<P>::B[t];
                const float cdd = vals[m][9+t] - mdd[t];
                const float ydd = cdd * rs - (cd[a]*sdot[b] + cd[b]*sdot[a]) * rs * rs
                                  + y * cy[t];
                pf[9+t] += w3 * (ydd * gi);
            }
        }
        #pragma unroll
        for (int k = 0; k < NCH; ++k) pf[k] = wave_sum_dpp(pf[k]);
        if (lane == 63) {
            #pragma unroll
            for (int k = 0; k < NCH; ++k) red[w * NRED + k] = pf[k];
        }
        __syncthreads();
        if (tid < NCH)
            fin[tid] = (red[tid] + red[NRED + tid]) + (red[2*NRED + tid] + red[3*NRED + tid]);
        __syncthreads();
        if (tid == 0) {
            if (P == 0) {
                #pragma unroll
                for (int a = 0; a < 8; ++a) sJ[a] = fin[1 + a];
            }
            #pragma unroll
            for (int t = 0; t < NPR; ++t) sH[P * NPR + t] = fin[9 + t];
        }
    }
}

template<int P>
__device__ void run_pass(int tid, int lane, int w, const float (&q)[8],
        const float* __restrict__ W0, const float* __restrict__ b0,
        const float* __restrict__ g0, const float* __restrict__ be0,
        const float* __restrict__ b1, const float* __restrict__ g1,
        const float* __restrict__ be1,
        const float* __restrict__ b2, const float* __restrict__ g2,
        const float* __restrict__ be2,
        const _Float16* __restrict__ Wf,
        float w3x, float w3y,
        float* S, float* red, float* fin, float* sJ, float* sH)
{
    float vals[2][NCH];

    // ---- layer 0: q(8) -> 512 (no gemm); grads = W0 row, hess = 0
    #pragma unroll
    for (int m = 0; m < 2; ++m) {
        const int i = 2 * tid + m;
        const float4 wa = *(const float4*)(W0 + i * 8);
        const float4 wb = *(const float4*)(W0 + i * 8 + 4);
        vals[m][0] = b0[i]
            + wa.x*q[0] + wa.y*q[1] + wa.z*q[2] + wa.w*q[3]
            + wb.x*q[4] + wb.y*q[5] + wb.z*q[6] + wb.w*q[7];
        vals[m][1] = wa.x; vals[m][2] = wa.y; vals[m][3] = wa.z; vals[m][4] = wa.w;
        vals[m][5] = wb.x; vals[m][6] = wb.y; vals[m][7] = wb.z; vals[m][8] = wb.w;
        #pragma unroll
        for (int t = 0; t < NPR; ++t) vals[m][9+t] = 0.f;
    }
    ln_process<P, false>(vals, g0, be0, S, red, fin, sJ, sH, tid, lane, w, w3x, w3y);
    __syncthreads();

    // ---- layer 1
    gemm_mfma(S, Wf, Wf + 262144, w, lane);
    readback(vals, b1, S, tid);
    ln_process<P, false>(vals, g1, be1, S, red, fin, sJ, sH, tid, lane, w, w3x, w3y);
    __syncthreads();

    // ---- layer 2
    gemm_mfma(S, Wf + 524288, Wf + 786432, w, lane);
    readback(vals, b2, S, tid);
    ln_process<P, true>(vals, g2, be2, S, red, fin, sJ, sH, tid, lane, w, w3x, w3y);
    __syncthreads();
}

__global__ __launch_bounds__(TPB, 3)
void lnn_kernel(const float* __restrict__ x,
    const float* __restrict__ W0, const float* __restrict__ b0,
    const float* __restrict__ g0, const float* __restrict__ be0,
    const float* __restrict__ b1, const float* __restrict__ g1,
    const float* __restrict__ be1,
    const float* __restrict__ b2, const float* __restrict__ g2,
    const float* __restrict__ be2,
    const float* __restrict__ W3,
    const _Float16* __restrict__ Wf,
    float* __restrict__ out)
{
    __shared__ __align__(16) float S[NCH * SSTR];   // 45.4 KB: state / D-staging
    __shared__ __align__(16) float red[4 * NRED];
    __shared__ __align__(16) float fin[NRED + 3];
    __shared__ float sJ[8];
    __shared__ float sH[26];

    const int tid  = threadIdx.x;
    const int lane = tid & 63;
    const int w    = tid >> 6;
    const long sample = blockIdx.x;

    float q[8];
    #pragma unroll
    for (int a = 0; a < 8; ++a) q[a] = x[sample * 8 + a];
    const float w3x = W3[2 * tid], w3y = W3[2 * tid + 1];

    run_pass<0>(tid, lane, w, q, W0, b0, g0, be0, b1, g1, be1, b2, g2, be2,
                Wf, w3x, w3y, S, red, fin, sJ, sH);
    run_pass<1>(tid, lane, w, q, W0, b0, g0, be0, b1, g1, be1, b2, g2, be2,
                Wf, w3x, w3y, S, red, fin, sJ, sH);

    if (tid == 0) {
        const int off[4] = {0, 5, 11, 18};
        double Hd[26];
        for (int t = 0; t < 26; ++t) Hd[t] = (double)sH[t];
        double r[4];
        for (int k = 0; k < 4; ++k) {
            double s = (double)sJ[k];
            for (int j = 0; j < 4; ++j) s -= Hd[off[k] + j] * (double)q[4 + j];
            r[k] = s;
        }
        double A[4][5];
        for (int jj = 0; jj < 4; ++jj) {
            for (int k = 0; k < 4; ++k) {
                const int lo = (jj < k ? jj : k) + 4;
                const int hi = (jj < k ? k : jj) + 4;
                A[jj][k] = Hd[off[hi - 4] + lo];
            }
            A[jj][4] = r[jj];
        }
        for (int c = 0; c < 4; ++c) {
            int pr = c; double mx = fabs(A[c][c]);
            for (int rr = c + 1; rr < 4; ++rr)
                if (fabs(A[rr][c]) > mx) { mx = fabs(A[rr][c]); pr = rr; }
            if (pr != c)
                for (int cc = c; cc < 5; ++cc) {
                    double t = A[c][cc]; A[c][cc] = A[pr][cc]; A[pr][cc] = t;
                }
            const double pinv = 1.0 / A[c][c];
            for (int rr = 0; rr < 4; ++rr) if (rr != c) {
                const double f = A[rr][c] * pinv;
                for (int cc = c; cc < 5; ++cc) A[rr][cc] -= f * A[c][cc];
            }
        }
        #pragma unroll
        for (int k = 0; k < 4; ++k)
            out[sample * 4 + k] = (float)(A[k][4] / A[k][k]);
    }
}

extern "C" void kernel_launch(void* const* d_in, const int* in_sizes, int n_in,
                              void* d_out, int out_size, void* d_ws, size_t ws_size,
                              hipStream_t stream) {
    const float* x   = (const float*)d_in[0];
    const float* W0  = (const float*)d_in[1];
    const float* b0  = (const float*)d_in[2];
    const float* g0  = (const float*)d_in[3];
    const float* be0 = (const float*)d_in[4];
    const float* W1  = (const float*)d_in[5];
    const float* b1  = (const float*)d_in[6];
    const float* g1  = (const float*)d_in[7];
    const float* be1 = (const float*)d_in[8];
    const float* W2  = (const float*)d_in[9];
    const float* b2  = (const float*)d_in[10];
    const float* g2  = (const float*)d_in[11];
    const float* be2 = (const float*)d_in[12];
    const float* W3  = (const float*)d_in[13];
    float* out = (float*)d_out;

    _Float16* Wf = (_Float16*)d_ws;   // 2 MB: [W1hi|W1lo|W2hi|W2lo] fragment layout
    const int B = in_sizes[0] / 8;    // 16384

    hipLaunchKernelGGL(prep_kernel, dim3(2048), dim3(256), 0, stream, W1, W2, Wf);
    hipLaunchKernelGGL(lnn_kernel, dim3(B), dim3(TPB), 0, stream,
                       x, W0, b0, g0, be0, b1, g1, be1, b2, g2, be2, W3, Wf, out);
}